// Round 5
// baseline (120.730 us; speedup 1.0000x reference)
//
#include <hip/hip_runtime.h>
#include <hip/hip_cooperative_groups.h>

namespace cg = cooperative_groups;

typedef unsigned short ushort_t;
typedef unsigned int uint_t;
typedef __attribute__((ext_vector_type(8))) short short8;
typedef __attribute__((ext_vector_type(4))) float f32x4;

#define IN_DIM 256
#define OUT_DIM 256
#define BATCH 512
#define NSPL 11                 // GRID_SIZE + K bases
#define KSLOT 12                // 11 bases + 1 silu/residual slot
#define KDIM (IN_DIM * KSLOT)   // 3072
#define NTHREADS 32768          // 512 blocks * 64

__device__ __forceinline__ ushort_t f2bf(float f) {
  union { float f; uint_t i; } c; c.f = f;
  uint_t u = c.i;
  u = u + 0x7FFFu + ((u >> 16) & 1u);   // round-to-nearest-even
  return (ushort_t)(u >> 16);
}

// ---- GEMM pipeline macros: one stage = K-chunk of 128 (4 A short8 + 4 W short8 = 32 VGPR)
#define STAGE_DECL(S) short8 S##a0, S##a1, S##a2, S##a3, S##w0, S##w1, S##w2, S##w3;
#define STAGE_LOAD(S, KT)                                   \
  S##a0 = *(const short8*)(pa + (KT));                      \
  S##a1 = *(const short8*)(pa + (KT) + 32);                 \
  S##a2 = *(const short8*)(pa + (KT) + 64);                 \
  S##a3 = *(const short8*)(pa + (KT) + 96);                 \
  S##w0 = *(const short8*)(pw + (KT));                      \
  S##w1 = *(const short8*)(pw + (KT) + 32);                 \
  S##w2 = *(const short8*)(pw + (KT) + 64);                 \
  S##w3 = *(const short8*)(pw + (KT) + 96);
#define STAGE_MFMA(S, ACC)                                                        \
  ACC = __builtin_amdgcn_mfma_f32_16x16x32_bf16(S##a0, S##w0, ACC, 0, 0, 0);      \
  ACC = __builtin_amdgcn_mfma_f32_16x16x32_bf16(S##a1, S##w1, ACC, 0, 0, 0);      \
  ACC = __builtin_amdgcn_mfma_f32_16x16x32_bf16(S##a2, S##w2, ACC, 0, 0, 0);      \
  ACC = __builtin_amdgcn_mfma_f32_16x16x32_bf16(S##a3, S##w3, ACC, 0, 0, 0);

// One cooperative kernel: phase 1 builds A[512][3072], W[256][3072] (bf16);
// grid sync; phase 2 = out[512][256] = A · Wᵀ, one 16x16 tile per wave.
__global__ __launch_bounds__(64) void fused(const float* __restrict__ x,
                                            const float* __restrict__ coef,
                                            const float* __restrict__ rw,
                                            const float* __restrict__ uw,
                                            ushort_t* __restrict__ A,
                                            ushort_t* __restrict__ W,
                                            float* __restrict__ out) {
  const int lane = threadIdx.x;                 // 0..63 (one wave per block)
  const int T = blockIdx.x * 64 + lane;         // 0..32767

  // ================= Phase 1a: A cells (4 per thread, coalesced passes) =================
  for (int k = 0; k < 4; ++k) {
    const int cell = T + k * NTHREADS;          // b*256 + i
    const float xf = x[cell];

    float bas[14];
#pragma unroll
    for (int t = 0; t < 14; ++t) {
      const float gt = -1.75f + 0.25f * (float)t;
      bas[t] = (xf >= gt && xf < gt + 0.25f) ? 1.0f : 0.0f;
    }
#pragma unroll
    for (int j = 1; j <= 3; ++j) {
      const float inv = 1.0f / (0.25f * (float)j);
#pragma unroll
      for (int t = 0; t < 14 - j; ++t) {        // ascending in-place: reads old bas[t], old bas[t+1]
        const float gt = -1.75f + 0.25f * (float)t;
        bas[t] = (xf - gt) * inv * bas[t] +
                 ((gt + 0.25f * (float)(j + 1)) - xf) * inv * bas[t + 1];
      }
    }
    const float silu = xf / (1.0f + __expf(-xf));

    ushort_t v[KSLOT];
#pragma unroll
    for (int g = 0; g < NSPL; ++g) v[g] = f2bf(bas[g]);
    v[11] = f2bf(silu);

    uint_t* dst = (uint_t*)(A + (size_t)cell * KSLOT);   // 24B per cell
#pragma unroll
    for (int j = 0; j < 6; ++j) dst[j] = (uint_t)v[2 * j] | ((uint_t)v[2 * j + 1] << 16);
  }

  // ================= Phase 1b: W cells (2 per thread) =================
  for (int k = 0; k < 2; ++k) {
    const int cell = T + k * NTHREADS;          // o*256 + i
    const float u = uw[cell];
    const float r = rw[cell];
    const float* c = coef + (size_t)cell * NSPL;

    ushort_t v[KSLOT];
#pragma unroll
    for (int g = 0; g < NSPL; ++g) v[g] = f2bf(u * c[g]);
    v[11] = f2bf(r);

    uint_t* dst = (uint_t*)(W + (size_t)cell * KSLOT);
#pragma unroll
    for (int j = 0; j < 6; ++j) dst[j] = (uint_t)v[2 * j] | ((uint_t)v[2 * j + 1] << 16);
  }

  __threadfence();                // device-scope release of A/W
  cg::this_grid().sync();         // all builds visible to all blocks

  // ================= Phase 2: GEMM, one 16x16 tile per wave =================
  const int b0 = (blockIdx.x & 31) * 16;        // M tile (32 tiles)
  const int o0 = (blockIdx.x >> 5) * 16;        // N tile (16 tiles)
  const int mn = lane & 15;
  const int kl = (lane >> 4) * 8;               // per-lane K sub-offset within a 32-chunk

  const ushort_t* pa = A + (size_t)(b0 + mn) * KDIM + kl;
  const ushort_t* pw = W + (size_t)(o0 + mn) * KDIM + kl;

  f32x4 acc0 = {0.f, 0.f, 0.f, 0.f};
  f32x4 acc1 = {0.f, 0.f, 0.f, 0.f};

  STAGE_DECL(s0) STAGE_DECL(s1) STAGE_DECL(s2) STAGE_DECL(s3)   // depth-4, 32 loads in flight

  STAGE_LOAD(s0, 0)
  STAGE_LOAD(s1, 128)
  STAGE_LOAD(s2, 256)
  STAGE_LOAD(s3, 384)

#pragma unroll
  for (int j = 0; j < 6; ++j) {                 // 6 iters x 512 K each
    const int nx = (j + 1) * 512;
    STAGE_MFMA(s0, acc0) if (j < 5) { STAGE_LOAD(s0, nx) }
    STAGE_MFMA(s1, acc1) if (j < 5) { STAGE_LOAD(s1, nx + 128) }
    STAGE_MFMA(s2, acc0) if (j < 5) { STAGE_LOAD(s2, nx + 256) }
    STAGE_MFMA(s3, acc1) if (j < 5) { STAGE_LOAD(s3, nx + 384) }
  }

  acc0[0] += acc1[0]; acc0[1] += acc1[1]; acc0[2] += acc1[2]; acc0[3] += acc1[3];

  // C/D layout (HW-verified): col = lane&15, row = (lane>>4)*4 + reg
  const int col = o0 + mn;
  const int rbase = b0 + (lane >> 4) * 4;
#pragma unroll
  for (int r = 0; r < 4; ++r) {
    out[(size_t)(rbase + r) * OUT_DIM + col] = acc0[r];
  }
}

extern "C" void kernel_launch(void* const* d_in, const int* in_sizes, int n_in,
                              void* d_out, int out_size, void* d_ws, size_t ws_size,
                              hipStream_t stream) {
  const float* x    = (const float*)d_in[0];
  const float* coef = (const float*)d_in[1];
  const float* rw   = (const float*)d_in[2];
  const float* uw   = (const float*)d_in[3];
  float* out = (float*)d_out;

  ushort_t* A = (ushort_t*)d_ws;                    // 512*3072*2 = 3.0 MB
  ushort_t* W = A + (size_t)BATCH * KDIM;           // 256*3072*2 = 1.5 MB

  void* args[] = {(void*)&x, (void*)&coef, (void*)&rw, (void*)&uw,
                  (void*)&A, (void*)&W, (void*)&out};
  hipLaunchCooperativeKernel((const void*)fused, dim3(512), dim3(64), args, 0, stream);
}

// Round 6
// 70.039 us; speedup vs baseline: 1.7238x; 1.7238x over previous
//
#include <hip/hip_runtime.h>

typedef unsigned short ushort_t;
typedef unsigned int uint_t;
typedef __attribute__((ext_vector_type(8))) short short8;
typedef __attribute__((ext_vector_type(4))) float f32x4;

#define IN_DIM 256
#define OUT_DIM 256
#define BATCH 512
#define NSPL 11                 // GRID_SIZE + K bases
#define KSLOT 12                // 11 bases + 1 silu/residual slot
#define KDIM (IN_DIM * KSLOT)   // 3072
#define MAGIC 1u

__device__ __forceinline__ ushort_t f2bf(float f) {
  union { float f; uint_t i; } c; c.f = f;
  uint_t u = c.i;
  u = u + 0x7FFFu + ((u >> 16) & 1u);   // round-to-nearest-even
  return (ushort_t)(u >> 16);
}

// One pipeline stage = K-chunk of 128 (4 A short8 + 4 W short8 = 32 VGPR)
#define STAGE_DECL(S) short8 S##a0, S##a1, S##a2, S##a3, S##w0, S##w1, S##w2, S##w3;
#define STAGE_LOAD(S, KT)                                   \
  S##a0 = *(const short8*)(pa + (KT));                      \
  S##a1 = *(const short8*)(pa + (KT) + 32);                 \
  S##a2 = *(const short8*)(pa + (KT) + 64);                 \
  S##a3 = *(const short8*)(pa + (KT) + 96);                 \
  S##w0 = *(const short8*)(pw + (KT));                      \
  S##w1 = *(const short8*)(pw + (KT) + 32);                 \
  S##w2 = *(const short8*)(pw + (KT) + 64);                 \
  S##w3 = *(const short8*)(pw + (KT) + 96);                 \
  __builtin_amdgcn_sched_barrier(0);   /* pin: prefetch loads stay issued HERE */
#define STAGE_MFMA(S, ACC)                                                        \
  ACC = __builtin_amdgcn_mfma_f32_16x16x32_bf16(S##a0, S##w0, ACC, 0, 0, 0);      \
  ACC = __builtin_amdgcn_mfma_f32_16x16x32_bf16(S##a1, S##w1, ACC, 0, 0, 0);      \
  ACC = __builtin_amdgcn_mfma_f32_16x16x32_bf16(S##a2, S##w2, ACC, 0, 0, 0);      \
  ACC = __builtin_amdgcn_mfma_f32_16x16x32_bf16(S##a3, S##w3, ACC, 0, 0, 0);

// Single kernel, 512 blocks x 64 threads.
// Block B: builds A row B (512 rows); blocks >=256 also build W row B-256 (256 rows).
// Release flag per row; each block then acquires the 32 flags for its 16x16 GEMM tile.
__global__ __launch_bounds__(64, 4) void fused(const float* __restrict__ x,
                                               const float* __restrict__ coef,
                                               const float* __restrict__ rw,
                                               const float* __restrict__ uw,
                                               ushort_t* __restrict__ A,
                                               ushort_t* __restrict__ W,
                                               uint_t* __restrict__ flags,
                                               float* __restrict__ out) {
  const int lane = threadIdx.x;     // 0..63, one wave per block
  const int B = blockIdx.x;         // 0..511

  // ---------------- Build phase ----------------
  {
    const int r = B;                               // A row
#pragma unroll
    for (int jc = 0; jc < 4; ++jc) {
      const int i = lane + jc * 64;                // coalesced x reads
      const float xf = x[r * IN_DIM + i];

      float bas[14];
#pragma unroll
      for (int t = 0; t < 14; ++t) {
        const float gt = -1.75f + 0.25f * (float)t;
        bas[t] = (xf >= gt && xf < gt + 0.25f) ? 1.0f : 0.0f;
      }
#pragma unroll
      for (int j = 1; j <= 3; ++j) {
        const float inv = 1.0f / (0.25f * (float)j);
#pragma unroll
        for (int t = 0; t < 14 - j; ++t) {         // ascending in-place
          const float gt = -1.75f + 0.25f * (float)t;
          bas[t] = (xf - gt) * inv * bas[t] +
                   ((gt + 0.25f * (float)(j + 1)) - xf) * inv * bas[t + 1];
        }
      }
      const float silu = xf / (1.0f + __expf(-xf));

      ushort_t v[KSLOT];
#pragma unroll
      for (int g = 0; g < NSPL; ++g) v[g] = f2bf(bas[g]);
      v[11] = f2bf(silu);

      uint_t* dst = (uint_t*)(A + (size_t)r * KDIM + i * KSLOT);
#pragma unroll
      for (int j = 0; j < 6; ++j) dst[j] = (uint_t)v[2 * j] | ((uint_t)v[2 * j + 1] << 16);
    }
  }
  if (B >= 256) {
    const int o = B - 256;                          // W row
#pragma unroll
    for (int jc = 0; jc < 4; ++jc) {
      const int i = lane + jc * 64;
      const size_t oi = (size_t)o * IN_DIM + i;
      const float u = uw[oi];
      const float r2 = rw[oi];
      const float* c = coef + oi * NSPL;

      ushort_t v[KSLOT];
#pragma unroll
      for (int g = 0; g < NSPL; ++g) v[g] = f2bf(u * c[g]);
      v[11] = f2bf(r2);

      uint_t* dst = (uint_t*)(W + oi * KSLOT);
#pragma unroll
      for (int j = 0; j < 6; ++j) dst[j] = (uint_t)v[2 * j] | ((uint_t)v[2 * j + 1] << 16);
    }
  }

  __threadfence();                                  // release A/W writes (device scope)
  if (lane == 0) {
    __hip_atomic_store(&flags[B], MAGIC, __ATOMIC_RELEASE, __HIP_MEMORY_SCOPE_AGENT);
    if (B >= 256)
      __hip_atomic_store(&flags[256 + B], MAGIC, __ATOMIC_RELEASE, __HIP_MEMORY_SCOPE_AGENT);
    // W-row flag for row o lives at flags[512 + o] = flags[256 + B]
  }

  // ---------------- Acquire the 32 rows this tile needs ----------------
  const int b0 = (B & 31) * 16;                     // M tile
  const int o0 = (B >> 5) * 16;                     // N tile
  if (lane < 32) {
    const int fidx = (lane < 16) ? (b0 + lane) : (512 + o0 + (lane - 16));
    while (__hip_atomic_load(&flags[fidx], __ATOMIC_RELAXED, __HIP_MEMORY_SCOPE_AGENT) != MAGIC) {
      __builtin_amdgcn_s_sleep(1);
    }
  }
  __threadfence();                                  // acquire (invalidate L1)

  // ---------------- GEMM: out tile = A[b0:b0+16][:] x W[o0:o0+16][:]^T ----------------
  const int mn = lane & 15;
  const int kl = (lane >> 4) * 8;                   // per-lane K sub-offset within a 32-chunk

  const ushort_t* pa = A + (size_t)(b0 + mn) * KDIM + kl;
  const ushort_t* pw = W + (size_t)(o0 + mn) * KDIM + kl;

  f32x4 acc0 = {0.f, 0.f, 0.f, 0.f};
  f32x4 acc1 = {0.f, 0.f, 0.f, 0.f};

  STAGE_DECL(s0) STAGE_DECL(s1)                     // depth-2: 16 loads in flight

  STAGE_LOAD(s0, 0)
  STAGE_LOAD(s1, 128)

#pragma unroll
  for (int c = 0; c < 24; ++c) {                    // 24 K-chunks of 128
    const int nxt = (c + 2) * 128;
    if (c & 1) {
      STAGE_MFMA(s1, acc1)
      if (nxt < KDIM) { STAGE_LOAD(s1, nxt) }
    } else {
      STAGE_MFMA(s0, acc0)
      if (nxt < KDIM) { STAGE_LOAD(s0, nxt) }
    }
  }

  acc0[0] += acc1[0]; acc0[1] += acc1[1]; acc0[2] += acc1[2]; acc0[3] += acc1[3];

  // C/D layout (HW-verified): col = lane&15, row = (lane>>4)*4 + reg
  const int col = o0 + mn;
  const int rbase = b0 + (lane >> 4) * 4;
#pragma unroll
  for (int r = 0; r < 4; ++r) {
    out[(size_t)(rbase + r) * OUT_DIM + col] = acc0[r];
  }
}

extern "C" void kernel_launch(void* const* d_in, const int* in_sizes, int n_in,
                              void* d_out, int out_size, void* d_ws, size_t ws_size,
                              hipStream_t stream) {
  const float* x    = (const float*)d_in[0];
  const float* coef = (const float*)d_in[1];
  const float* rw   = (const float*)d_in[2];
  const float* uw   = (const float*)d_in[3];
  float* out = (float*)d_out;

  ushort_t* A = (ushort_t*)d_ws;                            // 3.0 MB
  ushort_t* W = (ushort_t*)((char*)d_ws + 3u * 1024 * 1024); // 1.5 MB
  uint_t* flags = (uint_t*)((char*)d_ws + 6u * 1024 * 1024); // 768 words

  hipMemsetAsync(flags, 0, 768 * sizeof(uint_t), stream);   // deterministic flag reset (graph-safe)
  fused<<<512, 64, 0, stream>>>(x, coef, rw, uw, A, W, flags, out);
}

// Round 7
// 23.274 us; speedup vs baseline: 5.1874x; 3.0093x over previous
//
#include <hip/hip_runtime.h>

typedef unsigned short ushort_t;
typedef unsigned int uint_t;
typedef __attribute__((ext_vector_type(8))) short short8;
typedef __attribute__((ext_vector_type(4))) float f32x4;

#define IN_DIM 256
#define OUT_DIM 256
#define BATCH 512
#define NSPL 11                 // GRID_SIZE + K bases
#define KSLOT 12                // 11 bases + 1 silu/residual slot
#define KDIM (IN_DIM * KSLOT)   // 3072
#define KW 768                  // K per wave in split-K gemm (4 waves x 768 = 3072)

__device__ __forceinline__ ushort_t f2bf(float f) {
  union { float f; uint_t i; } c; c.f = f;
  uint_t u = c.i;
  u = u + 0x7FFFu + ((u >> 16) & 1u);   // round-to-nearest-even
  return (ushort_t)(u >> 16);
}

// ---- Kernel 1 (fused builder): blocks [0,512) build A rows, [512,768) build W rows ----
// A[b][i*12+g]: closed-form cubic B-spline (only 4 nonzero bases per x) + silu slot.
__global__ __launch_bounds__(256) void build_aw(const float* __restrict__ x,
                                                const float* __restrict__ coef,
                                                const float* __restrict__ rw,
                                                const float* __restrict__ uw,
                                                ushort_t* __restrict__ A,
                                                ushort_t* __restrict__ W) {
  const int bx = blockIdx.x;
  const int i = threadIdx.x;

  if (bx < BATCH) {
    const int b = bx;
    const float xf = x[b * IN_DIM + i];

    // knot interval: J = floor((x+1.75)/0.25); u in [0,1); nonzero bases g = J-3..J
    const float t = (xf + 1.75f) * 4.0f;
    const float fJ = floorf(t);
    const int J = (int)fJ;
    const float u = t - fJ;
    const bool inr = (J >= 0) && (J <= 13);

    const float u2 = u * u;
    const float u3 = u2 * u;
    const float um = 1.0f - u;
    const float n0 = um * um * um * (1.0f / 6.0f);              // basis J-3
    const float n1 = 0.5f * u3 - u2 + (4.0f / 6.0f);            // basis J-2
    const float n2 = -0.5f * u3 + 0.5f * u2 + 0.5f * u + (1.0f / 6.0f); // basis J-1
    const float n3 = u3 * (1.0f / 6.0f);                        // basis J

    const float silu = xf / (1.0f + __expf(-xf));

    ushort_t v[KSLOT];
#pragma unroll
    for (int g = 0; g < NSPL; ++g) {
      const int k = g - J + 3;                 // 0..3 -> n0..n3
      float val = 0.0f;
      if (inr) {
        if (k == 0) val = n0;
        else if (k == 1) val = n1;
        else if (k == 2) val = n2;
        else if (k == 3) val = n3;
      }
      v[g] = f2bf(val);
    }
    v[11] = f2bf(silu);

    uint_t* dst = (uint_t*)(A + (size_t)b * KDIM + i * KSLOT);
#pragma unroll
    for (int j = 0; j < 6; ++j) dst[j] = (uint_t)v[2 * j] | ((uint_t)v[2 * j + 1] << 16);
  } else {
    const int o = bx - BATCH;
    const size_t oi = (size_t)o * IN_DIM + i;
    const float uws = uw[oi];
    const float r = rw[oi];
    const float* c = coef + oi * NSPL;

    ushort_t v[KSLOT];
#pragma unroll
    for (int g = 0; g < NSPL; ++g) v[g] = f2bf(uws * c[g]);
    v[11] = f2bf(r);

    uint_t* dst = (uint_t*)(W + oi * KSLOT);
#pragma unroll
    for (int j = 0; j < 6; ++j) dst[j] = (uint_t)v[2 * j] | ((uint_t)v[2 * j + 1] << 16);
  }
}

// ---- Kernel 2: split-K GEMM. 512 blocks x 256 threads; block = one 16x16 tile;
// wave w accumulates K in [w*768,(w+1)*768); LDS reduce; 8 waves/CU hide L2 latency.
#define STAGE_DECL(S) short8 S##a0, S##a1, S##a2, S##a3, S##w0, S##w1, S##w2, S##w3;
#define STAGE_LOAD(S, KT)                                   \
  S##a0 = *(const short8*)(pa + (KT));                      \
  S##a1 = *(const short8*)(pa + (KT) + 32);                 \
  S##a2 = *(const short8*)(pa + (KT) + 64);                 \
  S##a3 = *(const short8*)(pa + (KT) + 96);                 \
  S##w0 = *(const short8*)(pw + (KT));                      \
  S##w1 = *(const short8*)(pw + (KT) + 32);                 \
  S##w2 = *(const short8*)(pw + (KT) + 64);                 \
  S##w3 = *(const short8*)(pw + (KT) + 96);                 \
  __builtin_amdgcn_sched_barrier(0);   /* keep prefetch issued here */
#define STAGE_MFMA(S, ACC)                                                        \
  ACC = __builtin_amdgcn_mfma_f32_16x16x32_bf16(S##a0, S##w0, ACC, 0, 0, 0);      \
  ACC = __builtin_amdgcn_mfma_f32_16x16x32_bf16(S##a1, S##w1, ACC, 0, 0, 0);      \
  ACC = __builtin_amdgcn_mfma_f32_16x16x32_bf16(S##a2, S##w2, ACC, 0, 0, 0);      \
  ACC = __builtin_amdgcn_mfma_f32_16x16x32_bf16(S##a3, S##w3, ACC, 0, 0, 0);

__global__ __launch_bounds__(256, 2) void gemm(const ushort_t* __restrict__ A,
                                               const ushort_t* __restrict__ W,
                                               float* __restrict__ out) {
  __shared__ f32x4 red[3][64];

  const int tid = threadIdx.x;
  const int lane = tid & 63;
  const int w = tid >> 6;                       // 0..3: K-slice owner
  const int B = blockIdx.x;
  const int b0 = (B & 31) * 16;                 // M tile
  const int o0 = (B >> 5) * 16;                 // N tile
  const int mn = lane & 15;
  const int kl = (lane >> 4) * 8;

  const ushort_t* pa = A + (size_t)(b0 + mn) * KDIM + w * KW + kl;
  const ushort_t* pw = W + (size_t)(o0 + mn) * KDIM + w * KW + kl;

  f32x4 acc0 = {0.f, 0.f, 0.f, 0.f};
  f32x4 acc1 = {0.f, 0.f, 0.f, 0.f};

  STAGE_DECL(s0) STAGE_DECL(s1)                 // depth-2 register pipeline

  STAGE_LOAD(s0, 0)
  STAGE_LOAD(s1, 128)
  STAGE_MFMA(s0, acc0) STAGE_LOAD(s0, 256)
  STAGE_MFMA(s1, acc1) STAGE_LOAD(s1, 384)
  STAGE_MFMA(s0, acc0) STAGE_LOAD(s0, 512)
  STAGE_MFMA(s1, acc1) STAGE_LOAD(s1, 640)
  STAGE_MFMA(s0, acc0)
  STAGE_MFMA(s1, acc1)

  acc0[0] += acc1[0]; acc0[1] += acc1[1]; acc0[2] += acc1[2]; acc0[3] += acc1[3];

  if (w > 0) red[w - 1][lane] = acc0;
  __syncthreads();

  if (w == 0) {
    const f32x4 r0 = red[0][lane];
    const f32x4 r1 = red[1][lane];
    const f32x4 r2 = red[2][lane];
#pragma unroll
    for (int q = 0; q < 4; ++q) acc0[q] += r0[q] + r1[q] + r2[q];

    // C/D layout (HW-verified): col = lane&15, row = (lane>>4)*4 + reg
    const int col = o0 + mn;
    const int rbase = b0 + (lane >> 4) * 4;
#pragma unroll
    for (int r = 0; r < 4; ++r) {
      out[(size_t)(rbase + r) * OUT_DIM + col] = acc0[r];
    }
  }
}

extern "C" void kernel_launch(void* const* d_in, const int* in_sizes, int n_in,
                              void* d_out, int out_size, void* d_ws, size_t ws_size,
                              hipStream_t stream) {
  const float* x    = (const float*)d_in[0];
  const float* coef = (const float*)d_in[1];
  const float* rw   = (const float*)d_in[2];
  const float* uw   = (const float*)d_in[3];
  float* out = (float*)d_out;

  ushort_t* A = (ushort_t*)d_ws;                             // 512*3072*2 = 3.0 MB
  ushort_t* W = A + (size_t)BATCH * KDIM;                    // 256*3072*2 = 1.5 MB

  build_aw<<<BATCH + OUT_DIM, IN_DIM, 0, stream>>>(x, coef, rw, uw, A, W);
  gemm<<<512, 256, 0, stream>>>(A, W, out);
}